// Round 7
// baseline (538.118 us; speedup 1.0000x reference)
//
#include <hip/hip_runtime.h>

typedef __bf16 bf16x4 __attribute__((ext_vector_type(4)));
typedef __bf16 bf16x8 __attribute__((ext_vector_type(8)));
typedef float  f32x4  __attribute__((ext_vector_type(4)));

constexpr int N_NODES = 50000;
constexpr int N_EDGES = 640000;
constexpr int NTILES  = 98;     // ceil(50000/512)
constexpr int NB_EDGE = 2500;   // edge blocks; 10000 tiles / 2500 = exactly 4 tiles each

__device__ __forceinline__ float leaky(float v) { return v >= 0.f ? v : 0.15f * v; }

// ---------------------------------------------------------------------------
// Prep: pack all weight matrices into MFMA B-fragment order (bf16) and fold
// the linear algebra:  M = eW2 @ nW[128:],  c = nb + eb2 @ nW[128:]
// ---------------------------------------------------------------------------
__global__ void prep_kernel(
    const float* __restrict__ e1W1, const float* __restrict__ e1b1,
    const float* __restrict__ e1W2, const float* __restrict__ e1b2,
    const float* __restrict__ n1W,  const float* __restrict__ n1b,
    const float* __restrict__ e2W1, const float* __restrict__ e2b1,
    const float* __restrict__ e2W2, const float* __restrict__ e2b2,
    const float* __restrict__ n2W,  const float* __restrict__ n2b,
    const float* __restrict__ muW,  const float* __restrict__ mub,
    const float* __restrict__ lvW,  const float* __restrict__ lvb,
    __bf16* __restrict__ packE, __bf16* __restrict__ packN1,
    __bf16* __restrict__ packN2, __bf16* __restrict__ packH,
    float* __restrict__ ebias, float* __restrict__ c1, float* __restrict__ c2,
    float* __restrict__ hbias)
{
    int bid = blockIdx.x;
    int lane = threadIdx.x;          // 64 threads
    int quad = lane >> 4, low = lane & 15;

    if (bid < 32) {                                   // edge B pack [64 x 256]
        int ct = bid >> 1, kt = bid & 1;
        for (int j = 0; j < 8; ++j) {
            int k = kt * 32 + quad * 8 + j;
            int n = ct * 16 + low;
            float v = (n < 128) ? e1W1[k * 128 + n] : e2W1[k * 128 + (n - 128)];
            packE[((ct * 2 + kt) * 64 + lane) * 8 + j] = (__bf16)v;
        }
    } else if (bid < 160) {                           // node1 / node2 B pack [256 x 128]
        bool is1 = bid < 96;
        int tile = bid - (is1 ? 32 : 96);
        const float* nW  = is1 ? n1W  : n2W;
        const float* eW2 = is1 ? e1W2 : e2W2;
        __bf16* dst = is1 ? packN1 : packN2;
        int ct = tile >> 3, kt = tile & 7;
        for (int j = 0; j < 8; ++j) {
            int k = kt * 32 + quad * 8 + j;
            int n = ct * 16 + low;
            float v;
            if (k < 128) {
                v = nW[k * 128 + n];
            } else {
                int i = k - 128;
                float acc = 0.f;
                for (int k2 = 0; k2 < 128; ++k2)
                    acc += eW2[i * 128 + k2] * nW[(128 + k2) * 128 + n];
                v = acc;
            }
            dst[((ct * 8 + kt) * 64 + lane) * 8 + j] = (__bf16)v;
        }
    } else if (bid < 192) {                           // head B pack [128 x 128]
        int tile = bid - 160;
        int ct = tile >> 2, kt = tile & 3;
        for (int j = 0; j < 8; ++j) {
            int k = kt * 32 + quad * 8 + j;
            int n = ct * 16 + low;
            float v = (n < 64) ? muW[k * 64 + n] : lvW[k * 64 + (n - 64)];
            packH[((ct * 4 + kt) * 64 + lane) * 8 + j] = (__bf16)v;
        }
    } else if (bid == 192 || bid == 193) {            // c1 / c2
        const float* nW  = (bid == 192) ? n1W  : n2W;
        const float* nb  = (bid == 192) ? n1b  : n2b;
        const float* eb2 = (bid == 192) ? e1b2 : e2b2;
        float* dst = (bid == 192) ? c1 : c2;
        for (int rep = 0; rep < 2; ++rep) {
            int j = lane + rep * 64;
            float acc = nb[j];
            for (int k = 0; k < 128; ++k)
                acc += eb2[k] * nW[(128 + k) * 128 + j];
            dst[j] = acc;
        }
    } else {                                          // biases
        for (int rep = 0; rep < 4; ++rep) {
            int j = lane + rep * 64;
            ebias[j] = (j < 128) ? e1b1[j] : e2b1[j - 128];
        }
        for (int rep = 0; rep < 2; ++rep) {
            int j = lane + rep * 64;
            hbias[j] = (j < 64) ? mub[j] : lvb[j - 64];
        }
    }
}

// --------------------------- counting sort by dst ---------------------------
__global__ void hist_kernel(const int* __restrict__ dstp, int* __restrict__ deg) {
    int e = blockIdx.x * 256 + threadIdx.x;
    if (e < N_EDGES) atomicAdd(&deg[dstp[e]], 1);
}

__global__ void scan_a(const int* __restrict__ deg, int* __restrict__ offs,
                       int* __restrict__ tileSum, float* __restrict__ degf) {
    __shared__ int s[512];
    int t = threadIdx.x, i = blockIdx.x * 512 + t;
    int v = (i < N_NODES) ? deg[i] : 0;
    if (i < N_NODES) degf[i] = (float)v;       // folded from old scan_c
    s[t] = v; __syncthreads();
    for (int off = 1; off < 512; off <<= 1) {
        int x = (t >= off) ? s[t - off] : 0;
        __syncthreads();
        s[t] += x;
        __syncthreads();
    }
    if (i < N_NODES) offs[i] = s[t] - v;       // exclusive within tile
    if (t == 511) tileSum[blockIdx.x] = s[511];
}

__global__ void scan_b(const int* __restrict__ tileSum, int* __restrict__ tileOff) {
    __shared__ int s[128];
    int t = threadIdx.x;
    int v = (t < NTILES) ? tileSum[t] : 0;
    s[t] = v; __syncthreads();
    for (int off = 1; off < 128; off <<= 1) {
        int x = (t >= off) ? s[t - off] : 0;
        __syncthreads();
        s[t] += x;
        __syncthreads();
    }
    if (t < NTILES) tileOff[t] = s[t] - v;
}

__global__ void scatter_kernel(const int* __restrict__ dstp, const int* __restrict__ offs,
                               const int* __restrict__ tileOff,
                               int* __restrict__ cursor, int* __restrict__ sorted,
                               int* __restrict__ sdst) {
    int e = blockIdx.x * 256 + threadIdx.x;
    if (e < N_EDGES) {
        int d = dstp[e];
        int p = offs[d] + tileOff[d >> 9] + atomicAdd(&cursor[d], 1);
        sorted[p] = e;
        sdst[p] = d;
    }
}

// ---------------------------------------------------------------------------
// Edge kernel v6: grid-stride software pipeline (2500 blocks x 4 tiles).
// As (staging) now ALIASES wave-0's L slice -> LDS 37.2 KB -> 4 blocks/CU.
// Costs one extra barrier (C) between GEMM1's As reads and wave-0's L writes.
// GEMM1: L[64x256] = leaky(ea @ [e1W1|e2W1] + b) -> LDS bf16 col-major.
// GEMM2: S_part[runs x 256] = R @ L (R from inclusive ballot popcount).
// ---------------------------------------------------------------------------
__global__ __launch_bounds__(256, 4) void edge_kernel(
    const float* __restrict__ edge_attr,
    const int* __restrict__ sorted, const int* __restrict__ sdst,
    const __bf16* __restrict__ packE,
    const float* __restrict__ ebias, float* __restrict__ S)
{
    __shared__ alignas(16) __bf16 Lball[4 * 64 * 72];  // 36864 B; slice 0 doubles as As
    __shared__ alignas(8) unsigned char runof_s[64];
    __shared__ int rundst_s[64];
    __shared__ int nruns_s;

    int tid = threadIdx.x;
    int w = tid >> 6, lane = tid & 63;
    int quad = lane >> 4, low = lane & 15;
    int r = tid >> 2, c0 = (tid & 3) * 16;

    // hoist weight fragments + bias into registers for all 4 tiles
    bf16x8 bfragE[2][4];
    #pragma unroll
    for (int kt = 0; kt < 2; ++kt)
        #pragma unroll
        for (int ct = 0; ct < 4; ++ct)
            bfragE[kt][ct] = *reinterpret_cast<const bf16x8*>(
                packE + (((w * 4 + ct) * 2 + kt) * 64 + lane) * 8);
    float bias_c[4];
    #pragma unroll
    for (int ct = 0; ct < 4; ++ct) bias_c[ct] = ebias[w * 64 + ct * 16 + low];

    __bf16* As = Lball;                    // alias: wave-0's L slice
    __bf16* Lb = &Lball[w * 4608];         // wave-local L slice (elements)

    constexpr int STRIDE = NB_EDGE * 64;
    int e0 = blockIdx.x * 64;

    // ---- prologue: tile 0 attr + dst, tile 1 indices ----
    float4 f0, f1, f2, f3;
    int md_c, ei_n, md_n;
    {
        int ei = sorted[e0 + r];
        md_c = sdst[e0 + lane];
        const float4* ap = reinterpret_cast<const float4*>(edge_attr + (size_t)ei * 64 + c0);
        f0 = ap[0]; f1 = ap[1]; f2 = ap[2]; f3 = ap[3];
    }
    ei_n = sorted[e0 + STRIDE + r];
    md_n = sdst[e0 + STRIDE + lane];

    #pragma unroll 1
    for (int it = 0; it < 4; ++it) {
        // ---- stage As from registers (bf16, row stride 72) ----
        {
            bf16x8 v0, v1;
            v0[0]=(__bf16)f0.x; v0[1]=(__bf16)f0.y; v0[2]=(__bf16)f0.z; v0[3]=(__bf16)f0.w;
            v0[4]=(__bf16)f1.x; v0[5]=(__bf16)f1.y; v0[6]=(__bf16)f1.z; v0[7]=(__bf16)f1.w;
            v1[0]=(__bf16)f2.x; v1[1]=(__bf16)f2.y; v1[2]=(__bf16)f2.z; v1[3]=(__bf16)f2.w;
            v1[4]=(__bf16)f3.x; v1[5]=(__bf16)f3.y; v1[6]=(__bf16)f3.z; v1[7]=(__bf16)f3.w;
            *reinterpret_cast<bf16x8*>(&As[r * 72 + c0])     = v0;
            *reinterpret_cast<bf16x8*>(&As[r * 72 + c0 + 8]) = v1;
        }

        // ---- run structure (wave 0) ----
        if (w == 0) {
            rundst_s[lane] = md_c;                     // defensive init: valid ids
            int dp = __shfl_up(md_c, 1);
            bool flag = (lane > 0) && (md_c != dp);
            unsigned long long mask = __ballot(flag);
            int rid = __popcll(mask & ((1ull << lane) - 1ull)) + (flag ? 1 : 0);
            runof_s[lane] = (unsigned char)rid;
            if (flag || lane == 0) rundst_s[rid] = md_c;
            if (lane == 0) nruns_s = __popcll(mask) + 1;
        }
        __syncthreads();                               // B: As + run info ready

        // ---- prefetch: tile it+1 attr, tile it+2 indices ----
        float4 g0{}, g1{}, g2{}, g3{};
        if (it < 3) {
            const float4* gp = reinterpret_cast<const float4*>(
                edge_attr + (size_t)ei_n * 64 + c0);
            g0 = gp[0]; g1 = gp[1]; g2 = gp[2]; g3 = gp[3];
        }
        int ei_nn = 0, md_nn = 0;
        if (it < 2) {
            int eo = e0 + (it + 2) * STRIDE;
            ei_nn = sorted[eo + r];
            md_nn = sdst[eo + lane];
        }

        // ---- GEMM1: C1[rt][ct], wave cols w*64 + ct*16 + low ----
        f32x4 C1[4][4] = {};
        #pragma unroll
        for (int kt = 0; kt < 2; ++kt)
            #pragma unroll
            for (int rt = 0; rt < 4; ++rt) {
                bf16x8 a = *reinterpret_cast<const bf16x8*>(
                    &As[(rt * 16 + low) * 72 + kt * 32 + quad * 8]);
                #pragma unroll
                for (int ct = 0; ct < 4; ++ct)
                    C1[rt][ct] = __builtin_amdgcn_mfma_f32_16x16x32_bf16(
                        a, bfragE[kt][ct], C1[rt][ct], 0, 0, 0);
            }
        __syncthreads();                               // C: all As reads done

        // ---- epilogue: bias + leaky -> wave-local Lb (col-major, stride 72) ----
        #pragma unroll
        for (int rt = 0; rt < 4; ++rt)
            #pragma unroll
            for (int ct = 0; ct < 4; ++ct) {
                bf16x4 v;
                #pragma unroll
                for (int rr = 0; rr < 4; ++rr)
                    v[rr] = (__bf16)leaky(C1[rt][ct][rr] + bias_c[ct]);
                *reinterpret_cast<bf16x4*>(
                    &Lb[(ct * 16 + low) * 72 + rt * 16 + quad * 4]) = v;
            }

        // ---- GEMM2: S_part = R @ L, atomics from C-fragments ----
        int nruns = nruns_s;
        for (int rt2 = 0; rt2 * 16 < nruns; ++rt2) {
            f32x4 C2[4] = {};
            #pragma unroll
            for (int kt = 0; kt < 2; ++kt) {
                uint2 rb2 = *reinterpret_cast<const uint2*>(&runof_s[kt * 32 + quad * 8]);
                unsigned target = (unsigned)(rt2 * 16 + low);
                bf16x8 a;
                #pragma unroll
                for (int j = 0; j < 8; ++j) {
                    unsigned byte = ((j < 4 ? (rb2.x >> (8 * j)) : (rb2.y >> (8 * (j - 4)))) & 0xFFu);
                    a[j] = (byte == target) ? (__bf16)1.0f : (__bf16)0.0f;
                }
                #pragma unroll
                for (int ct = 0; ct < 4; ++ct) {
                    bf16x8 b = *reinterpret_cast<const bf16x8*>(
                        &Lb[(ct * 16 + low) * 72 + kt * 32 + quad * 8]);
                    C2[ct] = __builtin_amdgcn_mfma_f32_16x16x32_bf16(a, b, C2[ct], 0, 0, 0);
                }
            }
            #pragma unroll
            for (int ct = 0; ct < 4; ++ct) {
                int col = w * 64 + ct * 16 + low;
                #pragma unroll
                for (int rr = 0; rr < 4; ++rr) {
                    int run = rt2 * 16 + quad * 4 + rr;
                    if (run < nruns) {
                        int node = rundst_s[run];
                        if ((unsigned)node < (unsigned)N_NODES)
                            unsafeAtomicAdd(&S[(size_t)node * 256 + col], C2[ct][rr]);
                    }
                }
            }
        }
        __syncthreads();                               // E: Lb reads done before next As

        // ---- rotate pipeline registers ----
        f0 = g0; f1 = g1; f2 = g2; f3 = g3;
        md_c = md_n; ei_n = ei_nn; md_n = md_nn;
    }
}

// ---------------------------------------------------------------------------
// Fused node pipeline: conv1 -> conv2 -> heads in ONE kernel.
// Row-local: h[r]=leaky(deg*x[r]@Wt1+deg*c1 + S1[r]@M1); same for g; out=g@[muW|lvW].
// h,g hand off through wave-local LDS (row-major bf16, stride 152: scalar b16
// writes from C-frags, vector b128 A-frag reads at 4-way bank conflict).
// h is stored pre-scaled by deg (folds conv2's row scaling; same rounding count).
// Kills 102 MB of h/g HBM round-trips and 2 launches.
// ---------------------------------------------------------------------------
__global__ __launch_bounds__(256) void node_fused(
    const float* __restrict__ x, const float* __restrict__ S,
    const float* __restrict__ degf,
    const __bf16* __restrict__ packN1, const __bf16* __restrict__ packN2,
    const __bf16* __restrict__ packH,
    const float* __restrict__ c1, const float* __restrict__ c2,
    const float* __restrict__ hbias,
    float* __restrict__ out)
{
    constexpr int HS = 152;                        // row stride (elements), 304 B
    __shared__ __bf16 Hs[4][16 * HS];              // 19456 B
    int w = threadIdx.x >> 6, lane = threadIdx.x & 63;
    int quad = lane >> 4, low = lane & 15;
    int rb = blockIdx.x * 64 + w * 16;

    int arow = rb + low;
    if (arow >= N_NODES) arow = N_NODES - 1;
    float ds = degf[arow];
    const float* xrow = x + (size_t)arow * 128;
    const float* Srow = S + (size_t)arow * 256;

    float deg4[4];
    #pragma unroll
    for (int rr = 0; rr < 4; ++rr) {
        int row = rb + quad * 4 + rr;
        deg4[rr] = degf[row < N_NODES ? row : N_NODES - 1];
    }

    __bf16* Hw = Hs[w];

    // ---- conv1: C = [deg*x | S1] @ packN1 ----
    f32x4 C[8] = {};
    #pragma unroll
    for (int kt = 0; kt < 8; ++kt) {
        const float* base = (kt < 4) ? (xrow + kt * 32 + quad * 8)
                                     : (Srow + (kt - 4) * 32 + quad * 8);
        float4 p0 = *reinterpret_cast<const float4*>(base);
        float4 p1 = *reinterpret_cast<const float4*>(base + 4);
        float m = (kt < 4) ? ds : 1.f;
        bf16x8 a;
        a[0]=(__bf16)(p0.x*m); a[1]=(__bf16)(p0.y*m); a[2]=(__bf16)(p0.z*m); a[3]=(__bf16)(p0.w*m);
        a[4]=(__bf16)(p1.x*m); a[5]=(__bf16)(p1.y*m); a[6]=(__bf16)(p1.z*m); a[7]=(__bf16)(p1.w*m);
        #pragma unroll
        for (int ct = 0; ct < 8; ++ct) {
            bf16x8 b = *reinterpret_cast<const bf16x8*>(packN1 + ((ct * 8 + kt) * 64 + lane) * 8);
            C[ct] = __builtin_amdgcn_mfma_f32_16x16x32_bf16(a, b, C[ct], 0, 0, 0);
        }
    }
    // epilogue: store deg*h (pre-scaled for conv2) row-major bf16
    #pragma unroll
    for (int ct = 0; ct < 8; ++ct) {
        int col = ct * 16 + low;
        float cb = c1[col];
        #pragma unroll
        for (int rr = 0; rr < 4; ++rr) {
            float v = leaky(C[ct][rr] + deg4[rr] * cb);
            Hw[(quad * 4 + rr) * HS + col] = (__bf16)(v * deg4[rr]);
        }
    }

    // ---- conv2: C2 = [deg*h | S2] @ packN2 ----
    f32x4 C2[8] = {};
    #pragma unroll
    for (int kt = 0; kt < 8; ++kt) {
        bf16x8 a;
        if (kt < 4) {
            a = *reinterpret_cast<const bf16x8*>(&Hw[low * HS + kt * 32 + quad * 8]);
        } else {
            const float* base = Srow + 128 + (kt - 4) * 32 + quad * 8;
            float4 p0 = *reinterpret_cast<const float4*>(base);
            float4 p1 = *reinterpret_cast<const float4*>(base + 4);
            a[0]=(__bf16)p0.x; a[1]=(__bf16)p0.y; a[2]=(__bf16)p0.z; a[3]=(__bf16)p0.w;
            a[4]=(__bf16)p1.x; a[5]=(__bf16)p1.y; a[6]=(__bf16)p1.z; a[7]=(__bf16)p1.w;
        }
        #pragma unroll
        for (int ct = 0; ct < 8; ++ct) {
            bf16x8 b = *reinterpret_cast<const bf16x8*>(packN2 + ((ct * 8 + kt) * 64 + lane) * 8);
            C2[ct] = __builtin_amdgcn_mfma_f32_16x16x32_bf16(a, b, C2[ct], 0, 0, 0);
        }
    }
    // epilogue: store g (unscaled) over the same LDS
    #pragma unroll
    for (int ct = 0; ct < 8; ++ct) {
        int col = ct * 16 + low;
        float cb = c2[col];
        #pragma unroll
        for (int rr = 0; rr < 4; ++rr) {
            float v = leaky(C2[ct][rr] + deg4[rr] * cb);
            Hw[(quad * 4 + rr) * HS + col] = (__bf16)v;
        }
    }

    // ---- heads: C3 = g @ [muW|lvW] ----
    f32x4 C3[8] = {};
    #pragma unroll
    for (int kt = 0; kt < 4; ++kt) {
        bf16x8 a = *reinterpret_cast<const bf16x8*>(&Hw[low * HS + kt * 32 + quad * 8]);
        #pragma unroll
        for (int ct = 0; ct < 8; ++ct) {
            bf16x8 b = *reinterpret_cast<const bf16x8*>(packH + ((ct * 4 + kt) * 64 + lane) * 8);
            C3[ct] = __builtin_amdgcn_mfma_f32_16x16x32_bf16(a, b, C3[ct], 0, 0, 0);
        }
    }
    #pragma unroll
    for (int ct = 0; ct < 8; ++ct) {
        int col = ct * 16 + low;
        float hb = hbias[col];
        #pragma unroll
        for (int rr = 0; rr < 4; ++rr) {
            int row = rb + quad * 4 + rr;
            if (row >= N_NODES) continue;
            float v = C3[ct][rr] + hb;
            if (col < 64) out[(size_t)row * 64 + col] = v;
            else          out[(size_t)N_NODES * 64 + (size_t)row * 64 + (col - 64)] = v;
        }
    }
}

// ---------------------------------------------------------------------------
extern "C" void kernel_launch(void* const* d_in, const int* in_sizes, int n_in,
                              void* d_out, int out_size, void* d_ws, size_t ws_size,
                              hipStream_t stream)
{
    const float* x     = (const float*)d_in[0];
    const int*   eidx  = (const int*)  d_in[1];
    const float* eattr = (const float*)d_in[2];
    const float* e1W1 = (const float*)d_in[3];
    const float* e1b1 = (const float*)d_in[4];
    const float* e1W2 = (const float*)d_in[5];
    const float* e1b2 = (const float*)d_in[6];
    const float* n1W  = (const float*)d_in[7];
    const float* n1b  = (const float*)d_in[8];
    const float* e2W1 = (const float*)d_in[9];
    const float* e2b1 = (const float*)d_in[10];
    const float* e2W2 = (const float*)d_in[11];
    const float* e2b2 = (const float*)d_in[12];
    const float* n2W  = (const float*)d_in[13];
    const float* n2b  = (const float*)d_in[14];
    const float* muW  = (const float*)d_in[15];
    const float* mub  = (const float*)d_in[16];
    const float* lvW  = (const float*)d_in[17];
    const float* lvb  = (const float*)d_in[18];

    const int* dstp = eidx + N_EDGES;   // edge_index row 1

    char* ws = (char*)d_ws;
    size_t off = 0;
    auto alloc = [&](size_t bytes) -> void* {
        void* p = ws + off;
        off = (off + bytes + 1023) & ~(size_t)1023;
        return p;
    };
    float* S       = (float*)alloc((size_t)N_NODES * 256 * 4);   // [N][256] S1|S2
    float* h       = (float*)alloc((size_t)N_NODES * 128 * 4);   // unused (layout keep)
    float* g       = (float*)alloc((size_t)N_NODES * 128 * 4);   // backs sdst
    int*   deg     = (int*)  alloc((size_t)N_NODES * 4);
    int*   cursor  = (int*)  alloc((size_t)N_NODES * 4);
    int*   offs    = (int*)  alloc((size_t)N_NODES * 4);
    float* degf    = (float*)alloc((size_t)N_NODES * 4);
    int*   sorted  = (int*)  alloc((size_t)N_EDGES * 4);
    int*   tileSum = (int*)  alloc(NTILES * 4);
    int*   tileOff = (int*)  alloc(NTILES * 4);
    __bf16* packE  = (__bf16*)alloc(32 * 64 * 8 * 2);
    __bf16* packN1 = (__bf16*)alloc(64 * 64 * 8 * 2);
    __bf16* packN2 = (__bf16*)alloc(64 * 64 * 8 * 2);
    __bf16* packH  = (__bf16*)alloc(32 * 64 * 8 * 2);
    float* ebias   = (float*)alloc(256 * 4);
    float* c1      = (float*)alloc(128 * 4);
    float* c2      = (float*)alloc(128 * 4);
    float* hbias   = (float*)alloc(128 * 4);
    (void)ws_size; (void)in_sizes; (void)n_in; (void)out_size; (void)h;

    int* sdst = (int*)g;   // g region is free scratch now (node pipeline fused)

    hipMemsetAsync(S, 0, (size_t)N_NODES * 256 * 4, stream);
    // deg + cursor are adjacent 1024-padded allocations -> one memset
    hipMemsetAsync(deg, 0, 2 * (((size_t)N_NODES * 4 + 1023) & ~(size_t)1023), stream);

    prep_kernel<<<195, 64, 0, stream>>>(e1W1, e1b1, e1W2, e1b2, n1W, n1b,
                                        e2W1, e2b1, e2W2, e2b2, n2W, n2b,
                                        muW, mub, lvW, lvb,
                                        packE, packN1, packN2, packH,
                                        ebias, c1, c2, hbias);

    hist_kernel<<<N_EDGES / 256, 256, 0, stream>>>(dstp, deg);
    scan_a<<<NTILES, 512, 0, stream>>>(deg, offs, tileSum, degf);
    scan_b<<<1, 128, 0, stream>>>(tileSum, tileOff);
    scatter_kernel<<<N_EDGES / 256, 256, 0, stream>>>(dstp, offs, tileOff, cursor, sorted, sdst);

    edge_kernel<<<NB_EDGE, 256, 0, stream>>>(eattr, sorted, sdst, packE, ebias, S);

    node_fused<<<(N_NODES + 63) / 64, 256, 0, stream>>>(
        x, S, degf, packN1, packN2, packH, c1, c2, hbias, (float*)d_out);
}

// Round 8
// 460.812 us; speedup vs baseline: 1.1678x; 1.1678x over previous
//
#include <hip/hip_runtime.h>

typedef __bf16 bf16x4 __attribute__((ext_vector_type(4)));
typedef __bf16 bf16x8 __attribute__((ext_vector_type(8)));
typedef float  f32x4  __attribute__((ext_vector_type(4)));

constexpr int N_NODES = 50000;
constexpr int N_EDGES = 640000;
constexpr int NTILES  = 98;     // ceil(50000/512)
constexpr int NB_EDGE = 2500;   // edge blocks; 10000 tiles / 2500 = exactly 4 tiles each

__device__ __forceinline__ float leaky(float v) { return v >= 0.f ? v : 0.15f * v; }

// ---------------------------------------------------------------------------
// Prep: pack all weight matrices into MFMA B-fragment order (bf16) and fold
// the linear algebra:  M = eW2 @ nW[128:],  c = nb + eb2 @ nW[128:]
// ---------------------------------------------------------------------------
__global__ void prep_kernel(
    const float* __restrict__ e1W1, const float* __restrict__ e1b1,
    const float* __restrict__ e1W2, const float* __restrict__ e1b2,
    const float* __restrict__ n1W,  const float* __restrict__ n1b,
    const float* __restrict__ e2W1, const float* __restrict__ e2b1,
    const float* __restrict__ e2W2, const float* __restrict__ e2b2,
    const float* __restrict__ n2W,  const float* __restrict__ n2b,
    const float* __restrict__ muW,  const float* __restrict__ mub,
    const float* __restrict__ lvW,  const float* __restrict__ lvb,
    __bf16* __restrict__ packE, __bf16* __restrict__ packN1,
    __bf16* __restrict__ packN2, __bf16* __restrict__ packH,
    float* __restrict__ ebias, float* __restrict__ c1, float* __restrict__ c2,
    float* __restrict__ hbias)
{
    int bid = blockIdx.x;
    int lane = threadIdx.x;          // 64 threads
    int quad = lane >> 4, low = lane & 15;

    if (bid < 32) {                                   // edge B pack [64 x 256]
        int ct = bid >> 1, kt = bid & 1;
        for (int j = 0; j < 8; ++j) {
            int k = kt * 32 + quad * 8 + j;
            int n = ct * 16 + low;
            float v = (n < 128) ? e1W1[k * 128 + n] : e2W1[k * 128 + (n - 128)];
            packE[((ct * 2 + kt) * 64 + lane) * 8 + j] = (__bf16)v;
        }
    } else if (bid < 160) {                           // node1 / node2 B pack [256 x 128]
        bool is1 = bid < 96;
        int tile = bid - (is1 ? 32 : 96);
        const float* nW  = is1 ? n1W  : n2W;
        const float* eW2 = is1 ? e1W2 : e2W2;
        __bf16* dst = is1 ? packN1 : packN2;
        int ct = tile >> 3, kt = tile & 7;
        for (int j = 0; j < 8; ++j) {
            int k = kt * 32 + quad * 8 + j;
            int n = ct * 16 + low;
            float v;
            if (k < 128) {
                v = nW[k * 128 + n];
            } else {
                int i = k - 128;
                float acc = 0.f;
                for (int k2 = 0; k2 < 128; ++k2)
                    acc += eW2[i * 128 + k2] * nW[(128 + k2) * 128 + n];
                v = acc;
            }
            dst[((ct * 8 + kt) * 64 + lane) * 8 + j] = (__bf16)v;
        }
    } else if (bid < 192) {                           // head B pack [128 x 128]
        int tile = bid - 160;
        int ct = tile >> 2, kt = tile & 3;
        for (int j = 0; j < 8; ++j) {
            int k = kt * 32 + quad * 8 + j;
            int n = ct * 16 + low;
            float v = (n < 64) ? muW[k * 64 + n] : lvW[k * 64 + (n - 64)];
            packH[((ct * 4 + kt) * 64 + lane) * 8 + j] = (__bf16)v;
        }
    } else if (bid == 192 || bid == 193) {            // c1 / c2
        const float* nW  = (bid == 192) ? n1W  : n2W;
        const float* nb  = (bid == 192) ? n1b  : n2b;
        const float* eb2 = (bid == 192) ? e1b2 : e2b2;
        float* dst = (bid == 192) ? c1 : c2;
        for (int rep = 0; rep < 2; ++rep) {
            int j = lane + rep * 64;
            float acc = nb[j];
            for (int k = 0; k < 128; ++k)
                acc += eb2[k] * nW[(128 + k) * 128 + j];
            dst[j] = acc;
        }
    } else {                                          // biases
        for (int rep = 0; rep < 4; ++rep) {
            int j = lane + rep * 64;
            ebias[j] = (j < 128) ? e1b1[j] : e2b1[j - 128];
        }
        for (int rep = 0; rep < 2; ++rep) {
            int j = lane + rep * 64;
            hbias[j] = (j < 64) ? mub[j] : lvb[j - 64];
        }
    }
}

// --------------------------- counting sort by dst ---------------------------
__global__ void hist_kernel(const int* __restrict__ dstp, int* __restrict__ deg) {
    int e = blockIdx.x * 256 + threadIdx.x;
    if (e < N_EDGES) atomicAdd(&deg[dstp[e]], 1);
}

__global__ void scan_a(const int* __restrict__ deg, int* __restrict__ offs,
                       int* __restrict__ tileSum, float* __restrict__ degf) {
    __shared__ int s[512];
    int t = threadIdx.x, i = blockIdx.x * 512 + t;
    int v = (i < N_NODES) ? deg[i] : 0;
    if (i < N_NODES) degf[i] = (float)v;       // folded from old scan_c
    s[t] = v; __syncthreads();
    for (int off = 1; off < 512; off <<= 1) {
        int x = (t >= off) ? s[t - off] : 0;
        __syncthreads();
        s[t] += x;
        __syncthreads();
    }
    if (i < N_NODES) offs[i] = s[t] - v;       // exclusive within tile
    if (t == 511) tileSum[blockIdx.x] = s[511];
}

__global__ void scan_b(const int* __restrict__ tileSum, int* __restrict__ tileOff) {
    __shared__ int s[128];
    int t = threadIdx.x;
    int v = (t < NTILES) ? tileSum[t] : 0;
    s[t] = v; __syncthreads();
    for (int off = 1; off < 128; off <<= 1) {
        int x = (t >= off) ? s[t - off] : 0;
        __syncthreads();
        s[t] += x;
        __syncthreads();
    }
    if (t < NTILES) tileOff[t] = s[t] - v;
}

__global__ void scatter_kernel(const int* __restrict__ dstp, const int* __restrict__ offs,
                               const int* __restrict__ tileOff,
                               int* __restrict__ cursor, int* __restrict__ sorted,
                               int* __restrict__ sdst) {
    int e = blockIdx.x * 256 + threadIdx.x;
    if (e < N_EDGES) {
        int d = dstp[e];
        int p = offs[d] + tileOff[d >> 9] + atomicAdd(&cursor[d], 1);
        sorted[p] = e;
        sdst[p] = d;
    }
}

// ---------------------------------------------------------------------------
// Edge kernel v7 = v6 with __launch_bounds__(256, 3).
// v6's (256,4) squeezed the kernel to 64 VGPR -> scratch spills / de-pipelined
// prefetch (FETCH 82->182 MB, WRITE 59->273 MB, dur 100->170 us). The live set
// (C1 64 + bfragE 32 + prefetch 32 VGPRs) needs the (256,3) budget. LDS stays
// 37.4 KB (As aliased into wave-0's L slice), so 4 blocks/CU remains reachable
// if the allocator lands <=128 VGPRs.
// ---------------------------------------------------------------------------
__global__ __launch_bounds__(256, 3) void edge_kernel(
    const float* __restrict__ edge_attr,
    const int* __restrict__ sorted, const int* __restrict__ sdst,
    const __bf16* __restrict__ packE,
    const float* __restrict__ ebias, float* __restrict__ S)
{
    __shared__ alignas(16) __bf16 Lball[4 * 64 * 72];  // 36864 B; slice 0 doubles as As
    __shared__ alignas(8) unsigned char runof_s[64];
    __shared__ int rundst_s[64];
    __shared__ int nruns_s;

    int tid = threadIdx.x;
    int w = tid >> 6, lane = tid & 63;
    int quad = lane >> 4, low = lane & 15;
    int r = tid >> 2, c0 = (tid & 3) * 16;

    // hoist weight fragments + bias into registers for all 4 tiles
    bf16x8 bfragE[2][4];
    #pragma unroll
    for (int kt = 0; kt < 2; ++kt)
        #pragma unroll
        for (int ct = 0; ct < 4; ++ct)
            bfragE[kt][ct] = *reinterpret_cast<const bf16x8*>(
                packE + (((w * 4 + ct) * 2 + kt) * 64 + lane) * 8);
    float bias_c[4];
    #pragma unroll
    for (int ct = 0; ct < 4; ++ct) bias_c[ct] = ebias[w * 64 + ct * 16 + low];

    __bf16* As = Lball;                    // alias: wave-0's L slice
    __bf16* Lb = &Lball[w * 4608];         // wave-local L slice (elements)

    constexpr int STRIDE = NB_EDGE * 64;
    int e0 = blockIdx.x * 64;

    // ---- prologue: tile 0 attr + dst, tile 1 indices ----
    float4 f0, f1, f2, f3;
    int md_c, ei_n, md_n;
    {
        int ei = sorted[e0 + r];
        md_c = sdst[e0 + lane];
        const float4* ap = reinterpret_cast<const float4*>(edge_attr + (size_t)ei * 64 + c0);
        f0 = ap[0]; f1 = ap[1]; f2 = ap[2]; f3 = ap[3];
    }
    ei_n = sorted[e0 + STRIDE + r];
    md_n = sdst[e0 + STRIDE + lane];

    #pragma unroll 1
    for (int it = 0; it < 4; ++it) {
        // ---- stage As from registers (bf16, row stride 72) ----
        {
            bf16x8 v0, v1;
            v0[0]=(__bf16)f0.x; v0[1]=(__bf16)f0.y; v0[2]=(__bf16)f0.z; v0[3]=(__bf16)f0.w;
            v0[4]=(__bf16)f1.x; v0[5]=(__bf16)f1.y; v0[6]=(__bf16)f1.z; v0[7]=(__bf16)f1.w;
            v1[0]=(__bf16)f2.x; v1[1]=(__bf16)f2.y; v1[2]=(__bf16)f2.z; v1[3]=(__bf16)f2.w;
            v1[4]=(__bf16)f3.x; v1[5]=(__bf16)f3.y; v1[6]=(__bf16)f3.z; v1[7]=(__bf16)f3.w;
            *reinterpret_cast<bf16x8*>(&As[r * 72 + c0])     = v0;
            *reinterpret_cast<bf16x8*>(&As[r * 72 + c0 + 8]) = v1;
        }

        // ---- run structure (wave 0) ----
        if (w == 0) {
            rundst_s[lane] = md_c;                     // defensive init: valid ids
            int dp = __shfl_up(md_c, 1);
            bool flag = (lane > 0) && (md_c != dp);
            unsigned long long mask = __ballot(flag);
            int rid = __popcll(mask & ((1ull << lane) - 1ull)) + (flag ? 1 : 0);
            runof_s[lane] = (unsigned char)rid;
            if (flag || lane == 0) rundst_s[rid] = md_c;
            if (lane == 0) nruns_s = __popcll(mask) + 1;
        }
        __syncthreads();                               // B: As + run info ready

        // ---- prefetch: tile it+1 attr, tile it+2 indices ----
        float4 g0{}, g1{}, g2{}, g3{};
        if (it < 3) {
            const float4* gp = reinterpret_cast<const float4*>(
                edge_attr + (size_t)ei_n * 64 + c0);
            g0 = gp[0]; g1 = gp[1]; g2 = gp[2]; g3 = gp[3];
        }
        int ei_nn = 0, md_nn = 0;
        if (it < 2) {
            int eo = e0 + (it + 2) * STRIDE;
            ei_nn = sorted[eo + r];
            md_nn = sdst[eo + lane];
        }

        // ---- GEMM1: C1[rt][ct], wave cols w*64 + ct*16 + low ----
        f32x4 C1[4][4] = {};
        #pragma unroll
        for (int kt = 0; kt < 2; ++kt)
            #pragma unroll
            for (int rt = 0; rt < 4; ++rt) {
                bf16x8 a = *reinterpret_cast<const bf16x8*>(
                    &As[(rt * 16 + low) * 72 + kt * 32 + quad * 8]);
                #pragma unroll
                for (int ct = 0; ct < 4; ++ct)
                    C1[rt][ct] = __builtin_amdgcn_mfma_f32_16x16x32_bf16(
                        a, bfragE[kt][ct], C1[rt][ct], 0, 0, 0);
            }
        __syncthreads();                               // C: all As reads done

        // ---- epilogue: bias + leaky -> wave-local Lb (col-major, stride 72) ----
        #pragma unroll
        for (int rt = 0; rt < 4; ++rt)
            #pragma unroll
            for (int ct = 0; ct < 4; ++ct) {
                bf16x4 v;
                #pragma unroll
                for (int rr = 0; rr < 4; ++rr)
                    v[rr] = (__bf16)leaky(C1[rt][ct][rr] + bias_c[ct]);
                *reinterpret_cast<bf16x4*>(
                    &Lb[(ct * 16 + low) * 72 + rt * 16 + quad * 4]) = v;
            }

        // ---- GEMM2: S_part = R @ L, atomics from C-fragments ----
        int nruns = nruns_s;
        for (int rt2 = 0; rt2 * 16 < nruns; ++rt2) {
            f32x4 C2[4] = {};
            #pragma unroll
            for (int kt = 0; kt < 2; ++kt) {
                uint2 rb2 = *reinterpret_cast<const uint2*>(&runof_s[kt * 32 + quad * 8]);
                unsigned target = (unsigned)(rt2 * 16 + low);
                bf16x8 a;
                #pragma unroll
                for (int j = 0; j < 8; ++j) {
                    unsigned byte = ((j < 4 ? (rb2.x >> (8 * j)) : (rb2.y >> (8 * (j - 4)))) & 0xFFu);
                    a[j] = (byte == target) ? (__bf16)1.0f : (__bf16)0.0f;
                }
                #pragma unroll
                for (int ct = 0; ct < 4; ++ct) {
                    bf16x8 b = *reinterpret_cast<const bf16x8*>(
                        &Lb[(ct * 16 + low) * 72 + kt * 32 + quad * 8]);
                    C2[ct] = __builtin_amdgcn_mfma_f32_16x16x32_bf16(a, b, C2[ct], 0, 0, 0);
                }
            }
            #pragma unroll
            for (int ct = 0; ct < 4; ++ct) {
                int col = w * 64 + ct * 16 + low;
                #pragma unroll
                for (int rr = 0; rr < 4; ++rr) {
                    int run = rt2 * 16 + quad * 4 + rr;
                    if (run < nruns) {
                        int node = rundst_s[run];
                        if ((unsigned)node < (unsigned)N_NODES)
                            unsafeAtomicAdd(&S[(size_t)node * 256 + col], C2[ct][rr]);
                    }
                }
            }
        }
        __syncthreads();                               // E: Lb reads done before next As

        // ---- rotate pipeline registers ----
        f0 = g0; f1 = g1; f2 = g2; f3 = g3;
        md_c = md_n; ei_n = ei_nn; md_n = md_nn;
    }
}

// ---------------------------------------------------------------------------
// Fused node pipeline: conv1 -> conv2 -> heads in ONE kernel.
// Row-local: h[r]=leaky(deg*x[r]@Wt1+deg*c1 + S1[r]@M1); same for g; out=g@[muW|lvW].
// h,g hand off through wave-local LDS (row-major bf16, stride 152).
// h is stored pre-scaled by deg (folds conv2's row scaling).
// ---------------------------------------------------------------------------
__global__ __launch_bounds__(256) void node_fused(
    const float* __restrict__ x, const float* __restrict__ S,
    const float* __restrict__ degf,
    const __bf16* __restrict__ packN1, const __bf16* __restrict__ packN2,
    const __bf16* __restrict__ packH,
    const float* __restrict__ c1, const float* __restrict__ c2,
    const float* __restrict__ hbias,
    float* __restrict__ out)
{
    constexpr int HS = 152;                        // row stride (elements), 304 B
    __shared__ __bf16 Hs[4][16 * HS];              // 19456 B
    int w = threadIdx.x >> 6, lane = threadIdx.x & 63;
    int quad = lane >> 4, low = lane & 15;
    int rb = blockIdx.x * 64 + w * 16;

    int arow = rb + low;
    if (arow >= N_NODES) arow = N_NODES - 1;
    float ds = degf[arow];
    const float* xrow = x + (size_t)arow * 128;
    const float* Srow = S + (size_t)arow * 256;

    float deg4[4];
    #pragma unroll
    for (int rr = 0; rr < 4; ++rr) {
        int row = rb + quad * 4 + rr;
        deg4[rr] = degf[row < N_NODES ? row : N_NODES - 1];
    }

    __bf16* Hw = Hs[w];

    // ---- conv1: C = [deg*x | S1] @ packN1 ----
    f32x4 C[8] = {};
    #pragma unroll
    for (int kt = 0; kt < 8; ++kt) {
        const float* base = (kt < 4) ? (xrow + kt * 32 + quad * 8)
                                     : (Srow + (kt - 4) * 32 + quad * 8);
        float4 p0 = *reinterpret_cast<const float4*>(base);
        float4 p1 = *reinterpret_cast<const float4*>(base + 4);
        float m = (kt < 4) ? ds : 1.f;
        bf16x8 a;
        a[0]=(__bf16)(p0.x*m); a[1]=(__bf16)(p0.y*m); a[2]=(__bf16)(p0.z*m); a[3]=(__bf16)(p0.w*m);
        a[4]=(__bf16)(p1.x*m); a[5]=(__bf16)(p1.y*m); a[6]=(__bf16)(p1.z*m); a[7]=(__bf16)(p1.w*m);
        #pragma unroll
        for (int ct = 0; ct < 8; ++ct) {
            bf16x8 b = *reinterpret_cast<const bf16x8*>(packN1 + ((ct * 8 + kt) * 64 + lane) * 8);
            C[ct] = __builtin_amdgcn_mfma_f32_16x16x32_bf16(a, b, C[ct], 0, 0, 0);
        }
    }
    // epilogue: store deg*h (pre-scaled for conv2) row-major bf16
    #pragma unroll
    for (int ct = 0; ct < 8; ++ct) {
        int col = ct * 16 + low;
        float cb = c1[col];
        #pragma unroll
        for (int rr = 0; rr < 4; ++rr) {
            float v = leaky(C[ct][rr] + deg4[rr] * cb);
            Hw[(quad * 4 + rr) * HS + col] = (__bf16)(v * deg4[rr]);
        }
    }

    // ---- conv2: C2 = [deg*h | S2] @ packN2 ----
    f32x4 C2[8] = {};
    #pragma unroll
    for (int kt = 0; kt < 8; ++kt) {
        bf16x8 a;
        if (kt < 4) {
            a = *reinterpret_cast<const bf16x8*>(&Hw[low * HS + kt * 32 + quad * 8]);
        } else {
            const float* base = Srow + 128 + (kt - 4) * 32 + quad * 8;
            float4 p0 = *reinterpret_cast<const float4*>(base);
            float4 p1 = *reinterpret_cast<const float4*>(base + 4);
            a[0]=(__bf16)p0.x; a[1]=(__bf16)p0.y; a[2]=(__bf16)p0.z; a[3]=(__bf16)p0.w;
            a[4]=(__bf16)p1.x; a[5]=(__bf16)p1.y; a[6]=(__bf16)p1.z; a[7]=(__bf16)p1.w;
        }
        #pragma unroll
        for (int ct = 0; ct < 8; ++ct) {
            bf16x8 b = *reinterpret_cast<const bf16x8*>(packN2 + ((ct * 8 + kt) * 64 + lane) * 8);
            C2[ct] = __builtin_amdgcn_mfma_f32_16x16x32_bf16(a, b, C2[ct], 0, 0, 0);
        }
    }
    // epilogue: store g (unscaled) over the same LDS
    #pragma unroll
    for (int ct = 0; ct < 8; ++ct) {
        int col = ct * 16 + low;
        float cb = c2[col];
        #pragma unroll
        for (int rr = 0; rr < 4; ++rr) {
            float v = leaky(C2[ct][rr] + deg4[rr] * cb);
            Hw[(quad * 4 + rr) * HS + col] = (__bf16)v;
        }
    }

    // ---- heads: C3 = g @ [muW|lvW] ----
    f32x4 C3[8] = {};
    #pragma unroll
    for (int kt = 0; kt < 4; ++kt) {
        bf16x8 a = *reinterpret_cast<const bf16x8*>(&Hw[low * HS + kt * 32 + quad * 8]);
        #pragma unroll
        for (int ct = 0; ct < 8; ++ct) {
            bf16x8 b = *reinterpret_cast<const bf16x8*>(packH + ((ct * 4 + kt) * 64 + lane) * 8);
            C3[ct] = __builtin_amdgcn_mfma_f32_16x16x32_bf16(a, b, C3[ct], 0, 0, 0);
        }
    }
    #pragma unroll
    for (int ct = 0; ct < 8; ++ct) {
        int col = ct * 16 + low;
        float hb = hbias[col];
        #pragma unroll
        for (int rr = 0; rr < 4; ++rr) {
            int row = rb + quad * 4 + rr;
            if (row >= N_NODES) continue;
            float v = C3[ct][rr] + hb;
            if (col < 64) out[(size_t)row * 64 + col] = v;
            else          out[(size_t)N_NODES * 64 + (size_t)row * 64 + (col - 64)] = v;
        }
    }
}

// ---------------------------------------------------------------------------
extern "C" void kernel_launch(void* const* d_in, const int* in_sizes, int n_in,
                              void* d_out, int out_size, void* d_ws, size_t ws_size,
                              hipStream_t stream)
{
    const float* x     = (const float*)d_in[0];
    const int*   eidx  = (const int*)  d_in[1];
    const float* eattr = (const float*)d_in[2];
    const float* e1W1 = (const float*)d_in[3];
    const float* e1b1 = (const float*)d_in[4];
    const float* e1W2 = (const float*)d_in[5];
    const float* e1b2 = (const float*)d_in[6];
    const float* n1W  = (const float*)d_in[7];
    const float* n1b  = (const float*)d_in[8];
    const float* e2W1 = (const float*)d_in[9];
    const float* e2b1 = (const float*)d_in[10];
    const float* e2W2 = (const float*)d_in[11];
    const float* e2b2 = (const float*)d_in[12];
    const float* n2W  = (const float*)d_in[13];
    const float* n2b  = (const float*)d_in[14];
    const float* muW  = (const float*)d_in[15];
    const float* mub  = (const float*)d_in[16];
    const float* lvW  = (const float*)d_in[17];
    const float* lvb  = (const float*)d_in[18];

    const int* dstp = eidx + N_EDGES;   // edge_index row 1

    char* ws = (char*)d_ws;
    size_t off = 0;
    auto alloc = [&](size_t bytes) -> void* {
        void* p = ws + off;
        off = (off + bytes + 1023) & ~(size_t)1023;
        return p;
    };
    float* S       = (float*)alloc((size_t)N_NODES * 256 * 4);   // [N][256] S1|S2
    float* h       = (float*)alloc((size_t)N_NODES * 128 * 4);   // unused (layout keep)
    float* g       = (float*)alloc((size_t)N_NODES * 128 * 4);   // backs sdst
    int*   deg     = (int*)  alloc((size_t)N_NODES * 4);
    int*   cursor  = (int*)  alloc((size_t)N_NODES * 4);
    int*   offs    = (int*)  alloc((size_t)N_NODES * 4);
    float* degf    = (float*)alloc((size_t)N_NODES * 4);
    int*   sorted  = (int*)  alloc((size_t)N_EDGES * 4);
    int*   tileSum = (int*)  alloc(NTILES * 4);
    int*   tileOff = (int*)  alloc(NTILES * 4);
    __bf16* packE  = (__bf16*)alloc(32 * 64 * 8 * 2);
    __bf16* packN1 = (__bf16*)alloc(64 * 64 * 8 * 2);
    __bf16* packN2 = (__bf16*)alloc(64 * 64 * 8 * 2);
    __bf16* packH  = (__bf16*)alloc(32 * 64 * 8 * 2);
    float* ebias   = (float*)alloc(256 * 4);
    float* c1      = (float*)alloc(128 * 4);
    float* c2      = (float*)alloc(128 * 4);
    float* hbias   = (float*)alloc(128 * 4);
    (void)ws_size; (void)in_sizes; (void)n_in; (void)out_size; (void)h;

    int* sdst = (int*)g;   // g region is free scratch (node pipeline fused)

    hipMemsetAsync(S, 0, (size_t)N_NODES * 256 * 4, stream);
    // deg + cursor are adjacent 1024-padded allocations -> one memset
    hipMemsetAsync(deg, 0, 2 * (((size_t)N_NODES * 4 + 1023) & ~(size_t)1023), stream);

    prep_kernel<<<195, 64, 0, stream>>>(e1W1, e1b1, e1W2, e1b2, n1W, n1b,
                                        e2W1, e2b1, e2W2, e2b2, n2W, n2b,
                                        muW, mub, lvW, lvb,
                                        packE, packN1, packN2, packH,
                                        ebias, c1, c2, hbias);

    hist_kernel<<<N_EDGES / 256, 256, 0, stream>>>(dstp, deg);
    scan_a<<<NTILES, 512, 0, stream>>>(deg, offs, tileSum, degf);
    scan_b<<<1, 128, 0, stream>>>(tileSum, tileOff);
    scatter_kernel<<<N_EDGES / 256, 256, 0, stream>>>(dstp, offs, tileOff, cursor, sorted, sdst);

    edge_kernel<<<NB_EDGE, 256, 0, stream>>>(eattr, sorted, sdst, packE, ebias, S);

    node_fused<<<(N_NODES + 63) / 64, 256, 0, stream>>>(
        x, S, degf, packN1, packN2, packH, c1, c2, hbias, (float*)d_out);
}